// Round 9
// baseline (341.365 us; speedup 1.0000x reference)
//
#include <hip/hip_runtime.h>
#include <hip/hip_bf16.h>

#define HW 9216
#define NPX 36864

typedef __attribute__((ext_vector_type(8))) short short8;
typedef __attribute__((ext_vector_type(4))) float f32x4;

static __device__ __forceinline__ unsigned short f2bf(float x) {
    union { __hip_bfloat16 h; unsigned short u; } c; c.h = __float2bfloat16(x); return c.u;
}
static __device__ __forceinline__ float bfl(unsigned int u){ return __uint_as_float(u << 16); }
static __device__ __forceinline__ float bfh(unsigned int u){ return __uint_as_float(u & 0xffff0000u); }

// ---------- weight pre-transposes ----------
__global__ __launch_bounds__(256) void prep_weights(
    const float* __restrict__ rw, const float* __restrict__ vw0,
    const float* __restrict__ vw1, const float* __restrict__ vw2,
    const float* __restrict__ fw,
    float* __restrict__ rwT, unsigned short* __restrict__ vwF, unsigned short* __restrict__ fwF)
{
    int idx = blockIdx.x * 256 + threadIdx.x;
    if (idx < 8192) {                       // reduce_w (64,128) -> rwT[i][c]
        int c = idx & 63, i = idx >> 6;
        rwT[idx] = rw[c * 128 + i];
    } else if (idx < 20480) {               // v_w -> MFMA B-fragment order vwF[lvl][nt][kf][lane][j]
        int e = idx - 8192;
        int j = e & 7, lane = (e >> 3) & 63, kf = (e >> 9) & 1, nt = (e >> 10) & 3, lvl = e >> 12;
        int co = nt * 16 + (lane & 15);
        int k = kf * 32 + (lane >> 4) * 8 + j;
        const float* vw = (lvl == 0) ? vw0 : ((lvl == 1) ? vw1 : vw2);
        vwF[e] = f2bf(vw[co * 64 + k]);
    } else if (idx < 167936) {              // fusion_w (64,256,3,3) -> B-fragment order fwF[kc][nt][lane][j]
        int e = idx - 20480;
        int j = e & 7, lane = (e >> 3) & 63, nt = (e >> 9) & 3, kc = e >> 11;   // kc in 0..71
        int co = nt * 16 + (lane & 15);
        int k = kc * 32 + ((lane >> 4) << 3) + j;   // global K index: tap*256 + ci
        int tap = k >> 8, ci = k & 255;
        fwF[e] = f2bf(fw[co * 2304 + ci * 9 + tap]);
    }
}

// ---------- transpose key->qT (NHWC fp32) and sup->fused[ch 0:64] (bf16) ----------
__global__ void pack_kernel(const float* __restrict__ key, const float* __restrict__ sup,
                            float* __restrict__ qT, __hip_bfloat16* __restrict__ fused)
{
    __shared__ float lk[32][33], ls[32][33];
    int tx = threadIdx.x, ty = threadIdx.y;
    int x0 = blockIdx.x * 32, c0 = blockIdx.y * 32;
    int z = blockIdx.z; int b = z / 96, y = z - b * 96;
    #pragma unroll
    for (int i = 0; i < 32; i += 8) {
        int c = c0 + ty + i;
        lk[ty + i][tx] = key[((b * 64 + c) * 96 + y) * 96 + x0 + tx];
        ls[ty + i][tx] = sup[((b * 64 + c) * 96 + y) * 96 + x0 + tx];
    }
    __syncthreads();
    #pragma unroll
    for (int i = 0; i < 32; i += 8) {
        int px = (b * 96 + y) * 96 + x0 + ty + i;
        qT[px * 64 + c0 + tx]     = lk[tx][ty + i];
        fused[px * 256 + c0 + tx] = __hip_bfloat16(ls[tx][ty + i]);
    }
}

// ---------- shifted grouped 3x3 conv, LDS-staged, wave-uniform out-channel ----------
__global__ __launch_bounds__(256) void shift_smooth(const float* __restrict__ sup,
    const float* __restrict__ w, const float* __restrict__ bias, float* __restrict__ smooth)
{
    __shared__ __align__(16) float tile[8][34][36];
    int bid = blockIdx.x;                 // 576 = 4b * 8grp * 9sj * 2half
    int half = bid & 1;
    int sj   = (bid >> 1) % 9;
    int grp  = (bid / 18) & 7;
    int b    = bid / 144;
    int sby = sj / 3, sbx = sj % 3;
    int Y0 = sby * 32, X0 = sbx * 32;
    int sh = 3 * ((grp >= 5) - (grp < 3));
    int mm = (grp < 3) ? grp : ((grp < 5) ? ((grp == 3) ? 0 : 2) : (grp - 5));
    int sw = 3 * mm - 3;
    int t = threadIdx.x;

    const float* supg = sup + (size_t)(b * 64 + grp * 8) * HW;
    #pragma unroll
    for (int pp = 0; pp < 5; pp++) {
        int pos = pp * 256 + t;
        if (pos < 1156) {
            int r = pos / 34, u = pos - r * 34;
            int yy = Y0 - 1 + r, xx = X0 - 1 + u;
            int ys = yy - sh, xs = xx - sw;
            bool ok = (yy >= 0) & (yy < 96) & (xx >= 0) & (xx < 96) &
                      (ys >= 0) & (ys < 96) & (xs >= 0) & (xs < 96);
            int addr = ok ? (ys * 96 + xs) : 0;
            #pragma unroll
            for (int ic = 0; ic < 8; ic++) {
                float v = supg[(size_t)ic * HW + addr];
                tile[ic][r][u] = ok ? v : 0.f;
            }
        }
    }
    __syncthreads();

    int c = __builtin_amdgcn_readfirstlane(grp * 8 + half * 4 + (t >> 6));
    int lane = t & 63;
    int ty4 = lane >> 3, tx4 = lane & 7;
    int py0 = ty4 * 4, x0r = tx4 * 4;

    float bz = bias[c];
    float acc[4][4];
    #pragma unroll
    for (int jr = 0; jr < 4; jr++)
        #pragma unroll
        for (int j = 0; j < 4; j++) acc[jr][j] = bz;

    const float* wp = w + c * 72;
    for (int ic = 0; ic < 8; ic++) {
        float wr[9];
        #pragma unroll
        for (int q = 0; q < 9; q++) wr[q] = wp[ic * 9 + q];
        #pragma unroll
        for (int rr = 0; rr < 6; rr++) {
            float4 fa = *(const float4*)&tile[ic][py0 + rr][x0r];
            float4 fb4 = *(const float4*)&tile[ic][py0 + rr][x0r + 4];
            float f[6] = {fa.x, fa.y, fa.z, fa.w, fb4.x, fb4.y};
            #pragma unroll
            for (int ky = 0; ky < 3; ky++) {
                int jr = rr - ky;
                if (jr >= 0 && jr < 4) {
                    #pragma unroll
                    for (int j = 0; j < 4; j++)
                        acc[jr][j] += wr[ky*3]*f[j] + wr[ky*3+1]*f[j+1] + wr[ky*3+2]*f[j+2];
                }
            }
        }
    }

    float* op = smooth + ((size_t)(b * 64 + c) * 96 + Y0 + py0) * 96 + X0 + x0r;
    #pragma unroll
    for (int jr = 0; jr < 4; jr++) {
        float4 st = {acc[jr][0], acc[jr][1], acc[jr][2], acc[jr][3]};
        *(float4*)(op + (size_t)jr * 96) = st;
    }
}

// ---------- 1x1 reduce conv (128->64): weights in LDS (broadcast), px per lane ----------
__global__ __launch_bounds__(256) void reduce_kernel(const float* __restrict__ sup,
    const float* __restrict__ smooth, const float* __restrict__ rwT,
    const float* __restrict__ rb, float* __restrict__ sup2)
{
    __shared__ __align__(16) float wlds[8192];   // rwT[i][c], 32 KB
    int t = threadIdx.x;
    #pragma unroll
    for (int e = 0; e < 8; e++) {
        int idx = (e * 256 + t) * 4;
        *(float4*)&wlds[idx] = *(const float4*)&rwT[idx];
    }
    __syncthreads();

    int lane = t & 63, wq = t >> 6;
    int px = blockIdx.x * 64 + lane;
    int b = px / HW; int rem = px - b * HW;
    const float* s1 = sup + (size_t)b * 64 * HW + rem;
    const float* s2 = smooth + (size_t)b * 64 * HW + rem;
    float acc[16];
    #pragma unroll
    for (int j = 0; j < 16; j++) acc[j] = rb[wq * 16 + j];

    #pragma unroll 8
    for (int i = 0; i < 64; i++) {
        float v = s1[i * HW];
        const float* wr = &wlds[i * 64 + wq * 16];
        float4 w0 = *(const float4*)wr, w1 = *(const float4*)(wr + 4);
        float4 w2 = *(const float4*)(wr + 8), w3 = *(const float4*)(wr + 12);
        acc[0] += w0.x * v;  acc[1] += w0.y * v;  acc[2] += w0.z * v;  acc[3] += w0.w * v;
        acc[4] += w1.x * v;  acc[5] += w1.y * v;  acc[6] += w1.z * v;  acc[7] += w1.w * v;
        acc[8] += w2.x * v;  acc[9] += w2.y * v;  acc[10] += w2.z * v; acc[11] += w2.w * v;
        acc[12] += w3.x * v; acc[13] += w3.y * v; acc[14] += w3.z * v; acc[15] += w3.w * v;
    }
    #pragma unroll 8
    for (int i = 0; i < 64; i++) {
        float v = s2[i * HW];
        const float* wr = &wlds[(64 + i) * 64 + wq * 16];
        float4 w0 = *(const float4*)wr, w1 = *(const float4*)(wr + 4);
        float4 w2 = *(const float4*)(wr + 8), w3 = *(const float4*)(wr + 12);
        acc[0] += w0.x * v;  acc[1] += w0.y * v;  acc[2] += w0.z * v;  acc[3] += w0.w * v;
        acc[4] += w1.x * v;  acc[5] += w1.y * v;  acc[6] += w1.z * v;  acc[7] += w1.w * v;
        acc[8] += w2.x * v;  acc[9] += w2.y * v;  acc[10] += w2.z * v; acc[11] += w2.w * v;
        acc[12] += w3.x * v; acc[13] += w3.y * v; acc[14] += w3.z * v; acc[15] += w3.w * v;
    }

    float* op = sup2 + (size_t)px * 64 + wq * 16;
    #pragma unroll
    for (int j = 0; j < 16; j += 4) { float4 st = {acc[j], acc[j+1], acc[j+2], acc[j+3]}; *(float4*)(op + j) = st; }
}

// ---------- fused 3-level neighborhood attention ----------
// lanes: pxl = wv*16 + (lane&15), qc = lane>>4 (shuffles xor 16/32)
template<int KS>
__device__ __forceinline__ void level_softmax(int qc, int y, int x, int ni7, int nj7,
        const _Float16* rpbl, const _Float16* dots_row, _Float16* out_row)
{
    constexpr int R = KS / 2, KK = KS * KS, NB = 2 * KS - 1;
    constexpr int NE = (KK + 3) / 4;
    int ni = min(max(y - R, 0), 96 - KS), nj = min(max(x - R, 0), 96 - KS);
    int di = ni - ni7, dj = nj - nj7;
    int br = KS - 1 + ni - y, bc = KS - 1 + nj - x;
    float sv[NE];
    float mx = -1e30f;
    #pragma unroll
    for (int i = 0; i < NE; i++) {
        int e = qc + i * 4;
        if (e < KK) {
            int ey = e / KS, ex = e - ey * KS;
            float s = (float)dots_row[(di + ey) * 7 + dj + ex] + (float)rpbl[(br + ey) * NB + bc + ex];
            sv[i] = s; mx = fmaxf(mx, s);
        } else sv[i] = -1e30f;
    }
    mx = fmaxf(mx, __shfl_xor(mx, 16)); mx = fmaxf(mx, __shfl_xor(mx, 32));
    float sum = 0.f;
    #pragma unroll
    for (int i = 0; i < NE; i++) { sv[i] = __expf(sv[i] - mx); sum += sv[i]; }
    sum += __shfl_xor(sum, 16); sum += __shfl_xor(sum, 32);
    float inv = 1.f / sum;
    #pragma unroll
    for (int i = 0; i < NE; i++) {
        int e = qc + i * 4;
        if (e < KK) out_row[e] = (_Float16)(sv[i] * inv);
    }
}

__global__ __launch_bounds__(256, 4) void natten_fused(
    const float* __restrict__ qT, const float* __restrict__ sup2,
    const unsigned short* __restrict__ vwF,
    const float* __restrict__ vb0, const float* __restrict__ vb1, const float* __restrict__ vb2,
    const float* __restrict__ rpb0, const float* __restrict__ rpb1, const float* __restrict__ rpb2,
    __hip_bfloat16* __restrict__ fused)
{
    __shared__ __align__(16) unsigned short khalo[196 * 72];  // 28224 B; reused as sproj
    __shared__ _Float16 dots[64][52];                         // 6656 B
    __shared__ _Float16 a3[64][12];                           // 1536 B
    __shared__ _Float16 a5[64][28];                           // 3584 B
    __shared__ _Float16 rlds[276];                            // 552 B

    int t = threadIdx.x;
    int bb = blockIdx.y;
    int tx0 = (blockIdx.x % 12) * 8, ty0 = (blockIdx.x / 12) * 8;
    const float* kb = sup2 + (size_t)bb * HW * 64;

    // stage rpb tables (fp16): [0:169)=rpb2, [169:250)=rpb1, [250:275)=rpb0
    // grid-stride: 275 entries > 256 threads!
    for (int e = t; e < 275; e += 256) {
        float v = (e < 169) ? rpb2[e] : ((e < 250) ? rpb1[e - 169] : rpb0[e - 250]);
        rlds[e] = (_Float16)v;
    }

    for (int it = 0; it < 13; it++) {
        int qidx = it * 256 + t;
        if (qidx < 3136) {
            int cq = qidx & 15, pos = qidx >> 4;
            int py = pos / 14, pxx = pos - py * 14;
            int gy = min(max(ty0 - 3 + py, 0), 95);
            int gx = min(max(tx0 - 3 + pxx, 0), 95);
            float4 v = *(const float4*)(kb + (((size_t)gy * 96 + gx) << 6) + cq * 4);
            ushort4 pk = {f2bf(v.x), f2bf(v.y), f2bf(v.z), f2bf(v.w)};
            *(ushort4*)&khalo[pos * 72 + cq * 4] = pk;
        }
    }
    __syncthreads();

    int lane = t & 63, wv = t >> 6;
    int pxl = wv * 16 + (lane & 15);
    int qc = lane >> 4;
    int pty = pxl >> 3, ptx = pxl & 7;
    int y = ty0 + pty, x = tx0 + ptx;
    int gpx = bb * HW + y * 96 + x;

    float qv[16];
    {
        const float* qp = qT + (size_t)gpx * 64 + qc * 16;
        #pragma unroll
        for (int j = 0; j < 16; j += 4) {
            float4 q4 = *(const float4*)(qp + j);
            qv[j] = q4.x; qv[j+1] = q4.y; qv[j+2] = q4.z; qv[j+3] = q4.w;
        }
    }

    int ni7 = min(max(y - 3, 0), 89), nj7 = min(max(x - 3, 0), 89);
    int ly = ni7 - (ty0 - 3), lx = nj7 - (tx0 - 3);

    // 49 shared dots, 4 partial accumulators each (short dep chains)
    for (int oy = 0; oy < 7; oy++) {
        #pragma unroll
        for (int ox = 0; ox < 7; ox++) {
            const unsigned short* kp = &khalo[((ly + oy) * 14 + lx + ox) * 72 + qc * 16];
            uint4 ka = *(const uint4*)kp;
            uint4 kc = *(const uint4*)(kp + 8);
            float p0 = qv[0]*bfl(ka.x) + qv[1]*bfh(ka.x) + qv[2]*bfl(ka.y) + qv[3]*bfh(ka.y);
            float p1 = qv[4]*bfl(ka.z) + qv[5]*bfh(ka.z) + qv[6]*bfl(ka.w) + qv[7]*bfh(ka.w);
            float p2 = qv[8]*bfl(kc.x) + qv[9]*bfh(kc.x) + qv[10]*bfl(kc.y) + qv[11]*bfh(kc.y);
            float p3 = qv[12]*bfl(kc.z) + qv[13]*bfh(kc.z) + qv[14]*bfl(kc.w) + qv[15]*bfh(kc.w);
            float d = (p0 + p1) + (p2 + p3);
            d += __shfl_xor(d, 16);
            d += __shfl_xor(d, 32);
            if (qc == 0) dots[pxl][oy * 7 + ox] = (_Float16)d;
        }
    }

    level_softmax<3>(qc, y, x, ni7, nj7, rlds + 250, &dots[pxl][0], &a3[pxl][0]);
    level_softmax<5>(qc, y, x, ni7, nj7, rlds + 169, &dots[pxl][0], &a5[pxl][0]);
    level_softmax<7>(qc, y, x, ni7, nj7, rlds,       &dots[pxl][0], &dots[pxl][0]);

    int ni5 = min(max(y - 2, 0), 91), nj5 = min(max(x - 2, 0), 91);
    int ni3 = min(max(y - 1, 0), 93), nj3 = min(max(x - 1, 0), 93);
    int di5 = ni5 - ni7, dj5 = nj5 - nj7, di3 = ni3 - ni7, dj3 = nj3 - nj7;

    float s2[3][16];
    #pragma unroll
    for (int l = 0; l < 3; l++)
        #pragma unroll
        for (int j = 0; j < 16; j++) s2[l][j] = 0.f;

    for (int oy = 0; oy < 7; oy++) {
        #pragma unroll
        for (int ox = 0; ox < 7; ox++) {
            const unsigned short* kp = &khalo[((ly + oy) * 14 + lx + ox) * 72 + qc * 16];
            uint4 ka = *(const uint4*)kp;
            uint4 kc = *(const uint4*)(kp + 8);
            float kv[16] = {bfl(ka.x), bfh(ka.x), bfl(ka.y), bfh(ka.y),
                            bfl(ka.z), bfh(ka.z), bfl(ka.w), bfh(ka.w),
                            bfl(kc.x), bfh(kc.x), bfl(kc.y), bfh(kc.y),
                            bfl(kc.z), bfh(kc.z), bfl(kc.w), bfh(kc.w)};
            float w7 = (float)dots[pxl][oy * 7 + ox];
            #pragma unroll
            for (int j = 0; j < 16; j++) s2[2][j] += w7 * kv[j];
            int e5y = oy - di5, e5x = ox - dj5;
            if ((unsigned)e5y < 5u && (unsigned)e5x < 5u) {
                float w5 = (float)a5[pxl][e5y * 5 + e5x];
                #pragma unroll
                for (int j = 0; j < 16; j++) s2[1][j] += w5 * kv[j];
            }
            int e3y = oy - di3, e3x = ox - dj3;
            if ((unsigned)e3y < 3u && (unsigned)e3x < 3u) {
                float w3 = (float)a3[pxl][e3y * 3 + e3x];
                #pragma unroll
                for (int j = 0; j < 16; j++) s2[0][j] += w3 * kv[j];
            }
        }
    }
    __syncthreads();   // khalo reads done -> reuse as sproj

    unsigned short* sproj = khalo;
    #pragma unroll
    for (int l = 0; l < 3; l++) {
        unsigned int pk[8];
        #pragma unroll
        for (int j = 0; j < 8; j++)
            pk[j] = (unsigned int)f2bf(s2[l][2*j]) | ((unsigned int)f2bf(s2[l][2*j+1]) << 16);
        unsigned int* dst = (unsigned int*)&sproj[(l * 64 + pxl) * 72 + qc * 16];
        uint4 s0 = {pk[0], pk[1], pk[2], pk[3]};
        uint4 s1 = {pk[4], pk[5], pk[6], pk[7]};
        *(uint4*)dst = s0;
        *(uint4*)(dst + 4) = s1;
    }
    __syncthreads();

    int lm = lane & 15, quad = lane >> 4;
    #pragma unroll
    for (int l = 0; l < 3; l++) {
        f32x4 acc[4];
        #pragma unroll
        for (int nt = 0; nt < 4; nt++) acc[nt] = (f32x4){0.f, 0.f, 0.f, 0.f};
        #pragma unroll
        for (int kf = 0; kf < 2; kf++) {
            short8 a = *(const short8*)&sproj[(l * 64 + wv * 16 + lm) * 72 + kf * 32 + quad * 8];
            #pragma unroll
            for (int nt = 0; nt < 4; nt++) {
                short8 bfr = *(const short8*)&vwF[(((l * 4 + nt) * 2 + kf) * 64 + lane) * 8];
                acc[nt] = __builtin_amdgcn_mfma_f32_16x16x32_bf16(a, bfr, acc[nt], 0, 0, 0);
            }
        }
        const float* vbl = (l == 0) ? vb0 : ((l == 1) ? vb1 : vb2);
        #pragma unroll
        for (int nt = 0; nt < 4; nt++)
            #pragma unroll
            for (int r = 0; r < 4; r++) {
                int p = wv * 16 + quad * 4 + r;
                int co = nt * 16 + lm;
                int py = p >> 3, pxx = p & 7;
                size_t off = ((size_t)(bb * HW + (ty0 + py) * 96 + tx0 + pxx) << 8) + (l + 1) * 64 + co;
                fused[off] = __hip_bfloat16(acc[nt][r] + vbl[co]);
            }
    }
}

// ---------- 3x3 fusion conv (256->64): LDS-staged implicit-GEMM bf16 MFMA ----------
__global__ __launch_bounds__(256) void fusion_mfma(
    const __hip_bfloat16* __restrict__ fB, const unsigned short* __restrict__ fwF,
    const float* __restrict__ fb, float* __restrict__ out)
{
    __shared__ __align__(16) unsigned short ah[108 * 72];   // 15552 B
    __shared__ float lds_out[64 * 66];                       // 16896 B
    int t = threadIdx.x;
    int wv = t >> 6, lane = t & 63, lm = lane & 15, quad = lane >> 4;
    int X0 = blockIdx.x * 16, Y0 = blockIdx.y * 4, b = blockIdx.z;
    const unsigned short* fBu = (const unsigned short*)fB;

    f32x4 acc[4] = {};

    for (int chunk = 0; chunk < 4; chunk++) {
        __syncthreads();
        #pragma unroll
        for (int ee = 0; ee < 4; ee++) {
            int e = ee * 256 + t;
            if (e < 864) {
                int seg = e & 7, hp = e >> 3;
                int hy = hp / 18, hx = hp - hy * 18;
                int gy = Y0 - 1 + hy, gx = X0 - 1 + hx;
                bool ok = (gy >= 0) & (gy < 96) & (gx >= 0) & (gx < 96);
                short8 v = {};
                if (ok) v = *(const short8*)(fBu + (((size_t)(b * HW + gy * 96 + gx)) << 8) + chunk * 64 + seg * 8);
                *(short8*)&ah[hp * 72 + seg * 8] = v;
            }
        }
        __syncthreads();
        #pragma unroll
        for (int ky = 0; ky < 3; ky++) {
            #pragma unroll
            for (int kx = 0; kx < 3; kx++) {
                #pragma unroll
                for (int kf = 0; kf < 2; kf++) {
                    short8 a = *(const short8*)&ah[((wv + ky) * 18 + lm + kx) * 72 + kf * 32 + quad * 8];
                    int kc = (ky * 3 + kx) * 8 + chunk * 2 + kf;
                    const unsigned short* bp = fwF + ((size_t)(kc * 4) * 64 + lane) * 8;
                    acc[0] = __builtin_amdgcn_mfma_f32_16x16x32_bf16(a, *(const short8*)(bp),        acc[0], 0, 0, 0);
                    acc[1] = __builtin_amdgcn_mfma_f32_16x16x32_bf16(a, *(const short8*)(bp + 512),  acc[1], 0, 0, 0);
                    acc[2] = __builtin_amdgcn_mfma_f32_16x16x32_bf16(a, *(const short8*)(bp + 1024), acc[2], 0, 0, 0);
                    acc[3] = __builtin_amdgcn_mfma_f32_16x16x32_bf16(a, *(const short8*)(bp + 1536), acc[3], 0, 0, 0);
                }
            }
        }
    }

    #pragma unroll
    for (int nt = 0; nt < 4; nt++)
        #pragma unroll
        for (int r = 0; r < 4; r++) {
            int p = wv * 16 + quad * 4 + r;
            int co = nt * 16 + lm;
            lds_out[co * 66 + p] = acc[nt][r];
        }
    __syncthreads();

    int p2 = t & 63, py = p2 >> 4, px2 = p2 & 15;
    float* ob = out + ((size_t)(b * 64) * 96 + Y0 + py) * 96 + X0 + px2;
    #pragma unroll 4
    for (int i = 0; i < 16; i++) {
        int co = (t >> 6) * 16 + i;
        float v = lds_out[co * 66 + p2] + fb[co];
        ob[(size_t)co * HW] = v > 0.f ? v : 0.f;
    }
}

extern "C" void kernel_launch(void* const* d_in, const int* in_sizes, int n_in,
                              void* d_out, int out_size, void* d_ws, size_t ws_size,
                              hipStream_t stream) {
    const float* sup = (const float*)d_in[0];
    const float* key = (const float*)d_in[1];
    const float* smw = (const float*)d_in[2];
    const float* smb = (const float*)d_in[3];
    const float* rw  = (const float*)d_in[4];
    const float* rb  = (const float*)d_in[5];
    const float *vw[3], *vb[3], *rpb[3];
    if (in_sizes[8] == 25) {
        for (int l = 0; l < 3; l++) {
            vw[l]  = (const float*)d_in[6 + 3 * l];
            vb[l]  = (const float*)d_in[7 + 3 * l];
            rpb[l] = (const float*)d_in[8 + 3 * l];
        }
    } else {
        for (int l = 0; l < 3; l++) {
            vw[l]  = (const float*)d_in[6 + 2 * l];
            vb[l]  = (const float*)d_in[7 + 2 * l];
            rpb[l] = (const float*)d_in[12 + l];
        }
    }
    const float* fw = (const float*)d_in[15];
    const float* fb = (const float*)d_in[16];
    float* out = (float*)d_out;

    float* wsf    = (float*)d_ws;
    float* smooth = wsf;                                    // 2359296 f
    float* sup2   = wsf + 2359296;                          // 2359296 f (NHWC)
    float* qT     = wsf + 4718592;                          // 2359296 f (NHWC)
    float* rwT    = wsf + 7077888;                          // 8192 f
    unsigned short* vwF = (unsigned short*)(wsf + 7086080); // 12288 bf16
    __hip_bfloat16* fusedB = (__hip_bfloat16*)(wsf + 7092224);  // 9437184 bf16
    unsigned short* fwF    = (unsigned short*)(wsf + 11810816); // 147456 bf16

    prep_weights<<<dim3(656), dim3(256), 0, stream>>>(rw, vw[0], vw[1], vw[2], fw, rwT, vwF, fwF);
    pack_kernel<<<dim3(3, 2, 384), dim3(32, 8), 0, stream>>>(key, sup, qT, fusedB);
    shift_smooth<<<dim3(576), dim3(256), 0, stream>>>(sup, smw, smb, smooth);
    reduce_kernel<<<dim3(576), dim3(256), 0, stream>>>(sup, smooth, rwT, rb, sup2);
    natten_fused<<<dim3(144, 4), dim3(256), 0, stream>>>(qT, sup2, vwF,
        vb[0], vb[1], vb[2], rpb[0], rpb[1], rpb[2], fusedB);
    fusion_mfma<<<dim3(6, 24, 4), dim3(256), 0, stream>>>(fusedB, fwF, fb, out);
}

// Round 10
// 225.285 us; speedup vs baseline: 1.5153x; 1.5153x over previous
//
#include <hip/hip_runtime.h>
#include <hip/hip_bf16.h>

#define HW 9216
#define NPX 36864

typedef __attribute__((ext_vector_type(8))) short short8;
typedef __attribute__((ext_vector_type(4))) float f32x4;

static __device__ __forceinline__ unsigned short f2bf(float x) {
    union { __hip_bfloat16 h; unsigned short u; } c; c.h = __float2bfloat16(x); return c.u;
}
static __device__ __forceinline__ float bfl(unsigned int u){ return __uint_as_float(u << 16); }
static __device__ __forceinline__ float bfh(unsigned int u){ return __uint_as_float(u & 0xffff0000u); }

// ---------- weight pre-transposes ----------
__global__ __launch_bounds__(256) void prep_weights(
    const float* __restrict__ rw, const float* __restrict__ vw0,
    const float* __restrict__ vw1, const float* __restrict__ vw2,
    const float* __restrict__ fw,
    float* __restrict__ rwT, unsigned short* __restrict__ vwF, unsigned short* __restrict__ fwF)
{
    int idx = blockIdx.x * 256 + threadIdx.x;
    if (idx < 8192) {                       // reduce_w (64,128) -> rwT[i][c]
        int c = idx & 63, i = idx >> 6;
        rwT[idx] = rw[c * 128 + i];
    } else if (idx < 20480) {               // v_w -> MFMA B-fragment order vwF[lvl][nt][kf][lane][j]
        int e = idx - 8192;
        int j = e & 7, lane = (e >> 3) & 63, kf = (e >> 9) & 1, nt = (e >> 10) & 3, lvl = e >> 12;
        int co = nt * 16 + (lane & 15);
        int k = kf * 32 + (lane >> 4) * 8 + j;
        const float* vw = (lvl == 0) ? vw0 : ((lvl == 1) ? vw1 : vw2);
        vwF[e] = f2bf(vw[co * 64 + k]);
    } else if (idx < 167936) {              // fusion_w (64,256,3,3) -> B-fragment order fwF[kc][nt][lane][j]
        int e = idx - 20480;
        int j = e & 7, lane = (e >> 3) & 63, nt = (e >> 9) & 3, kc = e >> 11;   // kc in 0..71
        int co = nt * 16 + (lane & 15);
        int k = kc * 32 + ((lane >> 4) << 3) + j;   // global K index: tap*256 + ci
        int tap = k >> 8, ci = k & 255;
        fwF[e] = f2bf(fw[co * 2304 + ci * 9 + tap]);
    }
}

// ---------- transpose key->qT (NHWC fp32) and sup->fused[ch 0:64] (bf16) ----------
__global__ void pack_kernel(const float* __restrict__ key, const float* __restrict__ sup,
                            float* __restrict__ qT, __hip_bfloat16* __restrict__ fused)
{
    __shared__ float lk[32][33], ls[32][33];
    int tx = threadIdx.x, ty = threadIdx.y;
    int x0 = blockIdx.x * 32, c0 = blockIdx.y * 32;
    int z = blockIdx.z; int b = z / 96, y = z - b * 96;
    #pragma unroll
    for (int i = 0; i < 32; i += 8) {
        int c = c0 + ty + i;
        lk[ty + i][tx] = key[((b * 64 + c) * 96 + y) * 96 + x0 + tx];
        ls[ty + i][tx] = sup[((b * 64 + c) * 96 + y) * 96 + x0 + tx];
    }
    __syncthreads();
    #pragma unroll
    for (int i = 0; i < 32; i += 8) {
        int px = (b * 96 + y) * 96 + x0 + ty + i;
        qT[px * 64 + c0 + tx]     = lk[tx][ty + i];
        fused[px * 256 + c0 + tx] = __hip_bfloat16(ls[tx][ty + i]);
    }
}

// ---------- shifted grouped 3x3 conv, LDS-staged, wave-uniform out-channel ----------
__global__ __launch_bounds__(256) void shift_smooth(const float* __restrict__ sup,
    const float* __restrict__ w, const float* __restrict__ bias, float* __restrict__ smooth)
{
    __shared__ __align__(16) float tile[8][34][36];
    int bid = blockIdx.x;                 // 576 = 4b * 8grp * 9sj * 2half
    int half = bid & 1;
    int sj   = (bid >> 1) % 9;
    int grp  = (bid / 18) & 7;
    int b    = bid / 144;
    int sby = sj / 3, sbx = sj % 3;
    int Y0 = sby * 32, X0 = sbx * 32;
    int sh = 3 * ((grp >= 5) - (grp < 3));
    int mm = (grp < 3) ? grp : ((grp < 5) ? ((grp == 3) ? 0 : 2) : (grp - 5));
    int sw = 3 * mm - 3;
    int t = threadIdx.x;

    const float* supg = sup + (size_t)(b * 64 + grp * 8) * HW;
    #pragma unroll
    for (int pp = 0; pp < 5; pp++) {
        int pos = pp * 256 + t;
        if (pos < 1156) {
            int r = pos / 34, u = pos - r * 34;
            int yy = Y0 - 1 + r, xx = X0 - 1 + u;
            int ys = yy - sh, xs = xx - sw;
            bool ok = (yy >= 0) & (yy < 96) & (xx >= 0) & (xx < 96) &
                      (ys >= 0) & (ys < 96) & (xs >= 0) & (xs < 96);
            int addr = ok ? (ys * 96 + xs) : 0;
            #pragma unroll
            for (int ic = 0; ic < 8; ic++) {
                float v = supg[(size_t)ic * HW + addr];
                tile[ic][r][u] = ok ? v : 0.f;
            }
        }
    }
    __syncthreads();

    int c = __builtin_amdgcn_readfirstlane(grp * 8 + half * 4 + (t >> 6));
    int lane = t & 63;
    int ty4 = lane >> 3, tx4 = lane & 7;
    int py0 = ty4 * 4, x0r = tx4 * 4;

    float bz = bias[c];
    float acc[4][4];
    #pragma unroll
    for (int jr = 0; jr < 4; jr++)
        #pragma unroll
        for (int j = 0; j < 4; j++) acc[jr][j] = bz;

    const float* wp = w + c * 72;
    for (int ic = 0; ic < 8; ic++) {
        float wr[9];
        #pragma unroll
        for (int q = 0; q < 9; q++) wr[q] = wp[ic * 9 + q];
        #pragma unroll
        for (int rr = 0; rr < 6; rr++) {
            float4 fa = *(const float4*)&tile[ic][py0 + rr][x0r];
            float4 fb4 = *(const float4*)&tile[ic][py0 + rr][x0r + 4];
            float f[6] = {fa.x, fa.y, fa.z, fa.w, fb4.x, fb4.y};
            #pragma unroll
            for (int ky = 0; ky < 3; ky++) {
                int jr = rr - ky;
                if (jr >= 0 && jr < 4) {
                    #pragma unroll
                    for (int j = 0; j < 4; j++)
                        acc[jr][j] += wr[ky*3]*f[j] + wr[ky*3+1]*f[j+1] + wr[ky*3+2]*f[j+2];
                }
            }
        }
    }

    float* op = smooth + ((size_t)(b * 64 + c) * 96 + Y0 + py0) * 96 + X0 + x0r;
    #pragma unroll
    for (int jr = 0; jr < 4; jr++) {
        float4 st = {acc[jr][0], acc[jr][1], acc[jr][2], acc[jr][3]};
        *(float4*)(op + (size_t)jr * 96) = st;
    }
}

// ---------- 1x1 reduce conv (128->64): weights in LDS (broadcast), px per lane ----------
__global__ __launch_bounds__(256) void reduce_kernel(const float* __restrict__ sup,
    const float* __restrict__ smooth, const float* __restrict__ rwT,
    const float* __restrict__ rb, float* __restrict__ sup2)
{
    __shared__ __align__(16) float wlds[8192];   // rwT[i][c], 32 KB
    int t = threadIdx.x;
    #pragma unroll
    for (int e = 0; e < 8; e++) {
        int idx = (e * 256 + t) * 4;
        *(float4*)&wlds[idx] = *(const float4*)&rwT[idx];
    }
    __syncthreads();

    int lane = t & 63, wq = t >> 6;
    int px = blockIdx.x * 64 + lane;
    int b = px / HW; int rem = px - b * HW;
    const float* s1 = sup + (size_t)b * 64 * HW + rem;
    const float* s2 = smooth + (size_t)b * 64 * HW + rem;
    float acc[16];
    #pragma unroll
    for (int j = 0; j < 16; j++) acc[j] = rb[wq * 16 + j];

    #pragma unroll 8
    for (int i = 0; i < 64; i++) {
        float v = s1[i * HW];
        const float* wr = &wlds[i * 64 + wq * 16];
        float4 w0 = *(const float4*)wr, w1 = *(const float4*)(wr + 4);
        float4 w2 = *(const float4*)(wr + 8), w3 = *(const float4*)(wr + 12);
        acc[0] += w0.x * v;  acc[1] += w0.y * v;  acc[2] += w0.z * v;  acc[3] += w0.w * v;
        acc[4] += w1.x * v;  acc[5] += w1.y * v;  acc[6] += w1.z * v;  acc[7] += w1.w * v;
        acc[8] += w2.x * v;  acc[9] += w2.y * v;  acc[10] += w2.z * v; acc[11] += w2.w * v;
        acc[12] += w3.x * v; acc[13] += w3.y * v; acc[14] += w3.z * v; acc[15] += w3.w * v;
    }
    #pragma unroll 8
    for (int i = 0; i < 64; i++) {
        float v = s2[i * HW];
        const float* wr = &wlds[(64 + i) * 64 + wq * 16];
        float4 w0 = *(const float4*)wr, w1 = *(const float4*)(wr + 4);
        float4 w2 = *(const float4*)(wr + 8), w3 = *(const float4*)(wr + 12);
        acc[0] += w0.x * v;  acc[1] += w0.y * v;  acc[2] += w0.z * v;  acc[3] += w0.w * v;
        acc[4] += w1.x * v;  acc[5] += w1.y * v;  acc[6] += w1.z * v;  acc[7] += w1.w * v;
        acc[8] += w2.x * v;  acc[9] += w2.y * v;  acc[10] += w2.z * v; acc[11] += w2.w * v;
        acc[12] += w3.x * v; acc[13] += w3.y * v; acc[14] += w3.z * v; acc[15] += w3.w * v;
    }

    float* op = sup2 + (size_t)px * 64 + wq * 16;
    #pragma unroll
    for (int j = 0; j < 16; j += 4) { float4 st = {acc[j], acc[j+1], acc[j+2], acc[j+3]}; *(float4*)(op + j) = st; }
}

// ---------- fused 3-level neighborhood attention ----------
// lanes: pxl = wv*16 + (lane&15), qc = lane>>4 (shuffles xor 16/32)
template<int KS>
__device__ __forceinline__ void level_softmax(int qc, int y, int x, int ni7, int nj7,
        const _Float16* rpbl, const _Float16* dots_row, _Float16* out_row)
{
    constexpr int R = KS / 2, KK = KS * KS, NB = 2 * KS - 1;
    constexpr int NE = (KK + 3) / 4;
    int ni = min(max(y - R, 0), 96 - KS), nj = min(max(x - R, 0), 96 - KS);
    int di = ni - ni7, dj = nj - nj7;
    int br = KS - 1 + ni - y, bc = KS - 1 + nj - x;
    float sv[NE];
    float mx = -1e30f;
    #pragma unroll
    for (int i = 0; i < NE; i++) {
        int e = qc + i * 4;
        if (e < KK) {
            int ey = e / KS, ex = e - ey * KS;
            float s = (float)dots_row[(di + ey) * 7 + dj + ex] + (float)rpbl[(br + ey) * NB + bc + ex];
            sv[i] = s; mx = fmaxf(mx, s);
        } else sv[i] = -1e30f;
    }
    mx = fmaxf(mx, __shfl_xor(mx, 16)); mx = fmaxf(mx, __shfl_xor(mx, 32));
    float sum = 0.f;
    #pragma unroll
    for (int i = 0; i < NE; i++) { sv[i] = __expf(sv[i] - mx); sum += sv[i]; }
    sum += __shfl_xor(sum, 16); sum += __shfl_xor(sum, 32);
    float inv = 1.f / sum;
    #pragma unroll
    for (int i = 0; i < NE; i++) {
        int e = qc + i * 4;
        if (e < KK) out_row[e] = (_Float16)(sv[i] * inv);
    }
}

__global__ __launch_bounds__(256) void natten_fused(
    const float* __restrict__ qT, const float* __restrict__ sup2,
    const unsigned short* __restrict__ vwF,
    const float* __restrict__ vb0, const float* __restrict__ vb1, const float* __restrict__ vb2,
    const float* __restrict__ rpb0, const float* __restrict__ rpb1, const float* __restrict__ rpb2,
    __hip_bfloat16* __restrict__ fused)
{
    __shared__ __align__(16) unsigned short khalo[196 * 72];  // 28224 B; reused as sproj
    __shared__ _Float16 dots[64][52];                         // 6656 B
    __shared__ _Float16 a3[64][12];                           // 1536 B
    __shared__ _Float16 a5[64][28];                           // 3584 B
    __shared__ _Float16 rlds[276];                            // 552 B

    int t = threadIdx.x;
    int bb = blockIdx.y;
    int tx0 = (blockIdx.x % 12) * 8, ty0 = (blockIdx.x / 12) * 8;
    const float* kb = sup2 + (size_t)bb * HW * 64;

    // stage rpb tables (fp16): [0:169)=rpb2, [169:250)=rpb1, [250:275)=rpb0
    for (int e = t; e < 275; e += 256) {
        float v = (e < 169) ? rpb2[e] : ((e < 250) ? rpb1[e - 169] : rpb0[e - 250]);
        rlds[e] = (_Float16)v;
    }

    for (int it = 0; it < 13; it++) {
        int qidx = it * 256 + t;
        if (qidx < 3136) {
            int cq = qidx & 15, pos = qidx >> 4;
            int py = pos / 14, pxx = pos - py * 14;
            int gy = min(max(ty0 - 3 + py, 0), 95);
            int gx = min(max(tx0 - 3 + pxx, 0), 95);
            float4 v = *(const float4*)(kb + (((size_t)gy * 96 + gx) << 6) + cq * 4);
            ushort4 pk = {f2bf(v.x), f2bf(v.y), f2bf(v.z), f2bf(v.w)};
            *(ushort4*)&khalo[pos * 72 + cq * 4] = pk;
        }
    }
    __syncthreads();

    int lane = t & 63, wv = t >> 6;
    int pxl = wv * 16 + (lane & 15);
    int qc = lane >> 4;
    int pty = pxl >> 3, ptx = pxl & 7;
    int y = ty0 + pty, x = tx0 + ptx;
    int gpx = bb * HW + y * 96 + x;

    float qv[16];
    {
        const float* qp = qT + (size_t)gpx * 64 + qc * 16;
        #pragma unroll
        for (int j = 0; j < 16; j += 4) {
            float4 q4 = *(const float4*)(qp + j);
            qv[j] = q4.x; qv[j+1] = q4.y; qv[j+2] = q4.z; qv[j+3] = q4.w;
        }
    }

    int ni7 = min(max(y - 3, 0), 89), nj7 = min(max(x - 3, 0), 89);
    int ly = ni7 - (ty0 - 3), lx = nj7 - (tx0 - 3);

    // 49 shared dots, 4 partial accumulators each (short dep chains)
    for (int oy = 0; oy < 7; oy++) {
        #pragma unroll
        for (int ox = 0; ox < 7; ox++) {
            const unsigned short* kp = &khalo[((ly + oy) * 14 + lx + ox) * 72 + qc * 16];
            uint4 ka = *(const uint4*)kp;
            uint4 kc = *(const uint4*)(kp + 8);
            float p0 = qv[0]*bfl(ka.x) + qv[1]*bfh(ka.x) + qv[2]*bfl(ka.y) + qv[3]*bfh(ka.y);
            float p1 = qv[4]*bfl(ka.z) + qv[5]*bfh(ka.z) + qv[6]*bfl(ka.w) + qv[7]*bfh(ka.w);
            float p2 = qv[8]*bfl(kc.x) + qv[9]*bfh(kc.x) + qv[10]*bfl(kc.y) + qv[11]*bfh(kc.y);
            float p3 = qv[12]*bfl(kc.z) + qv[13]*bfh(kc.z) + qv[14]*bfl(kc.w) + qv[15]*bfh(kc.w);
            float d = (p0 + p1) + (p2 + p3);
            d += __shfl_xor(d, 16);
            d += __shfl_xor(d, 32);
            if (qc == 0) dots[pxl][oy * 7 + ox] = (_Float16)d;
        }
    }

    level_softmax<3>(qc, y, x, ni7, nj7, rlds + 250, &dots[pxl][0], &a3[pxl][0]);
    level_softmax<5>(qc, y, x, ni7, nj7, rlds + 169, &dots[pxl][0], &a5[pxl][0]);
    level_softmax<7>(qc, y, x, ni7, nj7, rlds,       &dots[pxl][0], &dots[pxl][0]);

    int ni5 = min(max(y - 2, 0), 91), nj5 = min(max(x - 2, 0), 91);
    int ni3 = min(max(y - 1, 0), 93), nj3 = min(max(x - 1, 0), 93);
    int di5 = ni5 - ni7, dj5 = nj5 - nj7, di3 = ni3 - ni7, dj3 = nj3 - nj7;

    float s2[3][16];
    #pragma unroll
    for (int l = 0; l < 3; l++)
        #pragma unroll
        for (int j = 0; j < 16; j++) s2[l][j] = 0.f;

    for (int oy = 0; oy < 7; oy++) {
        #pragma unroll
        for (int ox = 0; ox < 7; ox++) {
            const unsigned short* kp = &khalo[((ly + oy) * 14 + lx + ox) * 72 + qc * 16];
            uint4 ka = *(const uint4*)kp;
            uint4 kc = *(const uint4*)(kp + 8);
            float kv[16] = {bfl(ka.x), bfh(ka.x), bfl(ka.y), bfh(ka.y),
                            bfl(ka.z), bfh(ka.z), bfl(ka.w), bfh(ka.w),
                            bfl(kc.x), bfh(kc.x), bfl(kc.y), bfh(kc.y),
                            bfl(kc.z), bfh(kc.z), bfl(kc.w), bfh(kc.w)};
            float w7 = (float)dots[pxl][oy * 7 + ox];
            #pragma unroll
            for (int j = 0; j < 16; j++) s2[2][j] += w7 * kv[j];
            int e5y = oy - di5, e5x = ox - dj5;
            if ((unsigned)e5y < 5u && (unsigned)e5x < 5u) {
                float w5 = (float)a5[pxl][e5y * 5 + e5x];
                #pragma unroll
                for (int j = 0; j < 16; j++) s2[1][j] += w5 * kv[j];
            }
            int e3y = oy - di3, e3x = ox - dj3;
            if ((unsigned)e3y < 3u && (unsigned)e3x < 3u) {
                float w3 = (float)a3[pxl][e3y * 3 + e3x];
                #pragma unroll
                for (int j = 0; j < 16; j++) s2[0][j] += w3 * kv[j];
            }
        }
    }
    __syncthreads();   // khalo reads done -> reuse as sproj

    unsigned short* sproj = khalo;
    #pragma unroll
    for (int l = 0; l < 3; l++) {
        unsigned int pk[8];
        #pragma unroll
        for (int j = 0; j < 8; j++)
            pk[j] = (unsigned int)f2bf(s2[l][2*j]) | ((unsigned int)f2bf(s2[l][2*j+1]) << 16);
        unsigned int* dst = (unsigned int*)&sproj[(l * 64 + pxl) * 72 + qc * 16];
        uint4 s0 = {pk[0], pk[1], pk[2], pk[3]};
        uint4 s1 = {pk[4], pk[5], pk[6], pk[7]};
        *(uint4*)dst = s0;
        *(uint4*)(dst + 4) = s1;
    }
    __syncthreads();

    int lm = lane & 15, quad = lane >> 4;
    #pragma unroll
    for (int l = 0; l < 3; l++) {
        f32x4 acc[4];
        #pragma unroll
        for (int nt = 0; nt < 4; nt++) acc[nt] = (f32x4){0.f, 0.f, 0.f, 0.f};
        #pragma unroll
        for (int kf = 0; kf < 2; kf++) {
            short8 a = *(const short8*)&sproj[(l * 64 + wv * 16 + lm) * 72 + kf * 32 + quad * 8];
            #pragma unroll
            for (int nt = 0; nt < 4; nt++) {
                short8 bfr = *(const short8*)&vwF[(((l * 4 + nt) * 2 + kf) * 64 + lane) * 8];
                acc[nt] = __builtin_amdgcn_mfma_f32_16x16x32_bf16(a, bfr, acc[nt], 0, 0, 0);
            }
        }
        const float* vbl = (l == 0) ? vb0 : ((l == 1) ? vb1 : vb2);
        #pragma unroll
        for (int nt = 0; nt < 4; nt++)
            #pragma unroll
            for (int r = 0; r < 4; r++) {
                int p = wv * 16 + quad * 4 + r;
                int co = nt * 16 + lm;
                int py = p >> 3, pxx = p & 7;
                size_t off = ((size_t)(bb * HW + (ty0 + py) * 96 + tx0 + pxx) << 8) + (l + 1) * 64 + co;
                fused[off] = __hip_bfloat16(acc[nt][r] + vbl[co]);
            }
    }
}

// ---------- 3x3 fusion conv (256->64): LDS-staged implicit-GEMM bf16 MFMA ----------
__global__ __launch_bounds__(256) void fusion_mfma(
    const __hip_bfloat16* __restrict__ fB, const unsigned short* __restrict__ fwF,
    const float* __restrict__ fb, float* __restrict__ out)
{
    __shared__ __align__(16) unsigned short ah[108 * 72];   // 15552 B
    __shared__ float lds_out[64 * 66];                       // 16896 B
    int t = threadIdx.x;
    int wv = t >> 6, lane = t & 63, lm = lane & 15, quad = lane >> 4;
    int X0 = blockIdx.x * 16, Y0 = blockIdx.y * 4, b = blockIdx.z;
    const unsigned short* fBu = (const unsigned short*)fB;

    f32x4 acc[4] = {};

    for (int chunk = 0; chunk < 4; chunk++) {
        __syncthreads();
        #pragma unroll
        for (int ee = 0; ee < 4; ee++) {
            int e = ee * 256 + t;
            if (e < 864) {
                int seg = e & 7, hp = e >> 3;
                int hy = hp / 18, hx = hp - hy * 18;
                int gy = Y0 - 1 + hy, gx = X0 - 1 + hx;
                bool ok = (gy >= 0) & (gy < 96) & (gx >= 0) & (gx < 96);
                short8 v = {};
                if (ok) v = *(const short8*)(fBu + (((size_t)(b * HW + gy * 96 + gx)) << 8) + chunk * 64 + seg * 8);
                *(short8*)&ah[hp * 72 + seg * 8] = v;
            }
        }
        __syncthreads();
        #pragma unroll
        for (int ky = 0; ky < 3; ky++) {
            #pragma unroll
            for (int kx = 0; kx < 3; kx++) {
                #pragma unroll
                for (int kf = 0; kf < 2; kf++) {
                    short8 a = *(const short8*)&ah[((wv + ky) * 18 + lm + kx) * 72 + kf * 32 + quad * 8];
                    int kc = (ky * 3 + kx) * 8 + chunk * 2 + kf;
                    const unsigned short* bp = fwF + ((size_t)(kc * 4) * 64 + lane) * 8;
                    acc[0] = __builtin_amdgcn_mfma_f32_16x16x32_bf16(a, *(const short8*)(bp),        acc[0], 0, 0, 0);
                    acc[1] = __builtin_amdgcn_mfma_f32_16x16x32_bf16(a, *(const short8*)(bp + 512),  acc[1], 0, 0, 0);
                    acc[2] = __builtin_amdgcn_mfma_f32_16x16x32_bf16(a, *(const short8*)(bp + 1024), acc[2], 0, 0, 0);
                    acc[3] = __builtin_amdgcn_mfma_f32_16x16x32_bf16(a, *(const short8*)(bp + 1536), acc[3], 0, 0, 0);
                }
            }
        }
    }

    #pragma unroll
    for (int nt = 0; nt < 4; nt++)
        #pragma unroll
        for (int r = 0; r < 4; r++) {
            int p = wv * 16 + quad * 4 + r;
            int co = nt * 16 + lm;
            lds_out[co * 66 + p] = acc[nt][r];
        }
    __syncthreads();

    int p2 = t & 63, py = p2 >> 4, px2 = p2 & 15;
    float* ob = out + ((size_t)(b * 64) * 96 + Y0 + py) * 96 + X0 + px2;
    #pragma unroll 4
    for (int i = 0; i < 16; i++) {
        int co = (t >> 6) * 16 + i;
        float v = lds_out[co * 66 + p2] + fb[co];
        ob[(size_t)co * HW] = v > 0.f ? v : 0.f;
    }
}

extern "C" void kernel_launch(void* const* d_in, const int* in_sizes, int n_in,
                              void* d_out, int out_size, void* d_ws, size_t ws_size,
                              hipStream_t stream) {
    const float* sup = (const float*)d_in[0];
    const float* key = (const float*)d_in[1];
    const float* smw = (const float*)d_in[2];
    const float* smb = (const float*)d_in[3];
    const float* rw  = (const float*)d_in[4];
    const float* rb  = (const float*)d_in[5];
    const float *vw[3], *vb[3], *rpb[3];
    if (in_sizes[8] == 25) {
        for (int l = 0; l < 3; l++) {
            vw[l]  = (const float*)d_in[6 + 3 * l];
            vb[l]  = (const float*)d_in[7 + 3 * l];
            rpb[l] = (const float*)d_in[8 + 3 * l];
        }
    } else {
        for (int l = 0; l < 3; l++) {
            vw[l]  = (const float*)d_in[6 + 2 * l];
            vb[l]  = (const float*)d_in[7 + 2 * l];
            rpb[l] = (const float*)d_in[12 + l];
        }
    }
    const float* fw = (const float*)d_in[15];
    const float* fb = (const float*)d_in[16];
    float* out = (float*)d_out;

    float* wsf    = (float*)d_ws;
    float* smooth = wsf;                                    // 2359296 f
    float* sup2   = wsf + 2359296;                          // 2359296 f (NHWC)
    float* qT     = wsf + 4718592;                          // 2359296 f (NHWC)
    float* rwT    = wsf + 7077888;                          // 8192 f
    unsigned short* vwF = (unsigned short*)(wsf + 7086080); // 12288 bf16
    __hip_bfloat16* fusedB = (__hip_bfloat16*)(wsf + 7092224);  // 9437184 bf16
    unsigned short* fwF    = (unsigned short*)(wsf + 11810816); // 147456 bf16

    prep_weights<<<dim3(656), dim3(256), 0, stream>>>(rw, vw[0], vw[1], vw[2], fw, rwT, vwF, fwF);
    pack_kernel<<<dim3(3, 2, 384), dim3(32, 8), 0, stream>>>(key, sup, qT, fusedB);
    shift_smooth<<<dim3(576), dim3(256), 0, stream>>>(sup, smw, smb, smooth);
    reduce_kernel<<<dim3(576), dim3(256), 0, stream>>>(sup, smooth, rwT, rb, sup2);
    natten_fused<<<dim3(144, 4), dim3(256), 0, stream>>>(qT, sup2, vwF,
        vb[0], vb[1], vb[2], rpb[0], rpb[1], rpb[2], fusedB);
    fusion_mfma<<<dim3(6, 24, 4), dim3(256), 0, stream>>>(fusedB, fwF, fb, out);
}